// Round 10
// baseline (667.798 us; speedup 1.0000x reference)
//
#include <hip/hip_runtime.h>

static constexpr int NE   = 4096;      // n_embed
static constexpr int ED   = 64;        // embed_dim
static constexpr int NTOK = 65536;     // 4*16*32*32
static constexpr int NCHUNK = 16;      // code-loop split factor
static constexpr int CPC  = NE / NCHUNK;   // codes per chunk = 256

typedef float  f32x4 __attribute__((ext_vector_type(4)));

// d_out offsets (float elements), outputs concatenated in return order:
// out(4194304), loss(1), perplexity(1), idx(65536), new_embed(262144),
// new_cs(4096), new_ea(262144)
static constexpr long O_OUT  = 0;
static constexpr long O_LOSS = 4194304;
static constexpr long O_PERP = 4194305;
static constexpr long O_IDX  = 4194306;
static constexpr long O_NEMB = 4259842;
static constexpr long O_NCS  = 4521986;
static constexpr long O_NEA  = 4526082;

// ws layout (bytes)
static constexpr size_t W_ACC   = 0;        // double[4]: [0]=loss [1]=n [2]=plog   (zeroed)
static constexpr size_t W_CNT   = 32;       // unsigned[4096] counts                (zeroed)
static constexpr size_t W_CUR   = 16416;    // unsigned[4096] scatter cursors       (zeroed)
static constexpr size_t W_OFF   = 32800;    // unsigned[4096] bucket start offsets
static constexpr size_t W_IDX   = 49184;    // int[65536]
static constexpr size_t W_BKT   = 311328;   // int[65536] token ids bucketed by code
static constexpr size_t W_LOSSP = 573472;   // double[16384] per-block loss partials
static constexpr size_t W_PKD   = 704544;   // uint64[65536] packed (d_bits<<32)|idx
static constexpr size_t W_AUG   = 1228832;  // float[4096*68]: [e row (64), bq, pad(3)]
static constexpr size_t W_ZERO_BYTES = 32800;   // acc + counts + cursors
static constexpr size_t W_PKD_BYTES  = 524288;  // 0xFF-init packed

// ---- augmented codebook: row n = [e_n[0..63], ||e_n||^2, pad] (stride 68) --
__global__ __launch_bounds__(256) void kAug(const float* __restrict__ e,
                                            float* __restrict__ aug) {
    int n = blockIdx.x * 256 + threadIdx.x;        // 0..4095
    const float* er = e + (n << 6);
    float* row = aug + (long)n * 68;
    // bq numerics: identical fmaf 4-partial chain to the 9x-passing kBsq
    float a0 = 0.f, a1 = 0.f, a2 = 0.f, a3 = 0.f;
#pragma unroll
    for (int k = 0; k < ED; k += 4) {
        a0 = fmaf(er[k+0], er[k+0], a0);
        a1 = fmaf(er[k+1], er[k+1], a1);
        a2 = fmaf(er[k+2], er[k+2], a2);
        a3 = fmaf(er[k+3], er[k+3], a3);
    }
#pragma unroll
    for (int k = 0; k < 16; ++k)
        ((f32x4*)row)[k] = ((const f32x4*)er)[k];
    row[64] = (a0 + a1) + (a2 + a3);
}

// 64 named z floats Z0..Z63
#define Z_EACH(F) \
    F(0)  F(1)  F(2)  F(3)  F(4)  F(5)  F(6)  F(7)  \
    F(8)  F(9)  F(10) F(11) F(12) F(13) F(14) F(15) \
    F(16) F(17) F(18) F(19) F(20) F(21) F(22) F(23) \
    F(24) F(25) F(26) F(27) F(28) F(29) F(30) F(31) \
    F(32) F(33) F(34) F(35) F(36) F(37) F(38) F(39) \
    F(40) F(41) F(42) F(43) F(44) F(45) F(46) F(47) \
    F(48) F(49) F(50) F(51) F(52) F(53) F(54) F(55) \
    F(56) F(57) F(58) F(59) F(60) F(61) F(62) F(63)

// scalar FMA line: dim K -> row vreg (48+K), chain v(113 + K%4).
// First 4 dims are v_mul == fmaf(z,e,+0) (only a -0/+0 difference, cannot
// affect the summed partials or the compare).
#define MULV(ACC, ZI, VR) "v_mul_f32 " ACC ", %[z" #ZI "], v" #VR "\n\t"
#define FMAV(ACC, ZI, VR) "v_fma_f32 " ACC ", %[z" #ZI "], v" #VR ", " ACC "\n\t"

// ---- argmin over a 256-code chunk, one thread per token -------------------
// grid = 4096 blocks: block = (tokenBlock<<4) | chunk
// r9 post-mortem: r4-r9 all plateau at the SMEM wall (~0.27 scalar-req/cyc/CU
// across configs; 160-190 cyc/iter lgkmcnt stall). VGPR_Count is granule-4
// (40 == 160 regs) so the AGPR-parking theory was wrong. Fix: stage the
// chunk's 256 aug-rows (69,632B) in LDS once per block; inner loop reads the
// wave-uniform row via ds_read_b128 broadcast (LDS pipe, ~120cyc) instead of
// s_load. Same bit-exact 4-chain fp32 FMA ordering as the passing kernels.
__global__ __launch_bounds__(256, 2) void kArgmin(const float* __restrict__ z,
                                                  const float* __restrict__ aug,
                                                  unsigned long long* __restrict__ packed) {
    __shared__ alignas(16) float lds[CPC * 68];    // 69,632 B
    int bid = blockIdx.x;
    int tb = bid >> 4;
    int chunk = bid & 15;

    // stage this chunk's aug rows into LDS (contiguous 69,632B, f32x4 copy)
    {
        const f32x4* src = (const f32x4*)(aug + (long)(chunk * CPC) * 68);
        f32x4* dst = (f32x4*)lds;
#pragma unroll
        for (int i = 0; i < 17; ++i)
            dst[threadIdx.x + i * 256] = src[threadIdx.x + i * 256];
    }
    __syncthreads();

    int t = tb * 256 + threadIdx.x;             // token id
    int b = t >> 14;                            // batch
    int s = t & 16383;                          // d*1024+h*32+w
    const float* zp = z + (long)b * 1048576 + s;

#define Z_LOAD(J) float Z##J = zp[J * 16384];
    Z_EACH(Z_LOAD)
#undef Z_LOAD

    // A = sum z^2: the reference 4-partial fmaf chain (bit-identical)
    float a0 = 0.f, a1 = 0.f, a2 = 0.f, a3 = 0.f;
#define Z_ASUM(J) { if ((J & 3) == 0) a0 = fmaf(Z##J, Z##J, a0); \
                    else if ((J & 3) == 1) a1 = fmaf(Z##J, Z##J, a1); \
                    else if ((J & 3) == 2) a2 = fmaf(Z##J, Z##J, a2); \
                    else a3 = fmaf(Z##J, Z##J, a3); }
    Z_EACH(Z_ASUM)
#undef Z_ASUM
    float A = (a0 + a1) + (a2 + a3);

    int c0i = chunk * CPC;
    float best = __builtin_inff();
    int bidx = c0i;
    // LDS byte offset of lds[0]: shared aperture is 4GiB-aligned, so the
    // low 32 bits of the generic pointer ARE the LDS offset.
    unsigned va0 = (unsigned)(unsigned long long)(&lds[0]);

    // Per iter: 17 ds_read (row dwords k -> v48+k, bq -> v112, broadcast),
    // 64 scalar v_fma in the reference's 4 round-robin chains v113..v116
    // (= d0..d3, ascending dims); combine (d0+d1)+(d2+d3);
    // d = fma(-2, dot, A+bq); strict-< min track; row stride 272B.
    asm volatile(
        "s_mov_b32 s32, 0\n\t"
        "v_mov_b32 v119, %[n0]\n\t"
        "1:\n\t"
        "ds_read_b128 v[48:51], %[va] offset:0\n\t"
        "ds_read_b128 v[52:55], %[va] offset:16\n\t"
        "ds_read_b128 v[56:59], %[va] offset:32\n\t"
        "ds_read_b128 v[60:63], %[va] offset:48\n\t"
        "ds_read_b128 v[64:67], %[va] offset:64\n\t"
        "ds_read_b128 v[68:71], %[va] offset:80\n\t"
        "ds_read_b128 v[72:75], %[va] offset:96\n\t"
        "ds_read_b128 v[76:79], %[va] offset:112\n\t"
        "ds_read_b128 v[80:83], %[va] offset:128\n\t"
        "ds_read_b128 v[84:87], %[va] offset:144\n\t"
        "ds_read_b128 v[88:91], %[va] offset:160\n\t"
        "ds_read_b128 v[92:95], %[va] offset:176\n\t"
        "ds_read_b128 v[96:99], %[va] offset:192\n\t"
        "ds_read_b128 v[100:103], %[va] offset:208\n\t"
        "ds_read_b128 v[104:107], %[va] offset:224\n\t"
        "ds_read_b128 v[108:111], %[va] offset:240\n\t"
        "ds_read_b32 v112, %[va] offset:256\n\t"
        "s_waitcnt lgkmcnt(0)\n\t"
        MULV("v113", 0, 48) MULV("v114", 1, 49) MULV("v115", 2, 50) MULV("v116", 3, 51)
        FMAV("v113", 4, 52) FMAV("v114", 5, 53) FMAV("v115", 6, 54) FMAV("v116", 7, 55)
        FMAV("v113", 8, 56) FMAV("v114", 9, 57) FMAV("v115", 10, 58) FMAV("v116", 11, 59)
        FMAV("v113", 12, 60) FMAV("v114", 13, 61) FMAV("v115", 14, 62) FMAV("v116", 15, 63)
        FMAV("v113", 16, 64) FMAV("v114", 17, 65) FMAV("v115", 18, 66) FMAV("v116", 19, 67)
        FMAV("v113", 20, 68) FMAV("v114", 21, 69) FMAV("v115", 22, 70) FMAV("v116", 23, 71)
        FMAV("v113", 24, 72) FMAV("v114", 25, 73) FMAV("v115", 26, 74) FMAV("v116", 27, 75)
        FMAV("v113", 28, 76) FMAV("v114", 29, 77) FMAV("v115", 30, 78) FMAV("v116", 31, 79)
        FMAV("v113", 32, 80) FMAV("v114", 33, 81) FMAV("v115", 34, 82) FMAV("v116", 35, 83)
        FMAV("v113", 36, 84) FMAV("v114", 37, 85) FMAV("v115", 38, 86) FMAV("v116", 39, 87)
        FMAV("v113", 40, 88) FMAV("v114", 41, 89) FMAV("v115", 42, 90) FMAV("v116", 43, 91)
        FMAV("v113", 44, 92) FMAV("v114", 45, 93) FMAV("v115", 46, 94) FMAV("v116", 47, 95)
        FMAV("v113", 48, 96) FMAV("v114", 49, 97) FMAV("v115", 50, 98) FMAV("v116", 51, 99)
        FMAV("v113", 52, 100) FMAV("v114", 53, 101) FMAV("v115", 54, 102) FMAV("v116", 55, 103)
        FMAV("v113", 56, 104) FMAV("v114", 57, 105) FMAV("v115", 58, 106) FMAV("v116", 59, 107)
        FMAV("v113", 60, 108) FMAV("v114", 61, 109) FMAV("v115", 62, 110) FMAV("v116", 63, 111)
        "v_add_f32 v117, v113, v114\n\t"
        "v_add_f32 v118, v115, v116\n\t"
        "v_add_f32 v117, v117, v118\n\t"
        "v_add_f32 v118, v112, %[A]\n\t"
        "v_fma_f32 v117, -2.0, v117, v118\n\t"
        "v_cmp_lt_f32 vcc, v117, %[best]\n\t"
        "v_cndmask_b32 %[best], %[best], v117, vcc\n\t"
        "v_cndmask_b32 %[bidx], %[bidx], v119, vcc\n\t"
        "v_add_u32 v119, 1, v119\n\t"
        "v_add_u32 %[va], 0x110, %[va]\n\t"
        "s_add_u32 s32, s32, 1\n\t"
        "s_cmp_lt_u32 s32, 0x100\n\t"
        "s_cbranch_scc1 1b\n\t"
        : [best]"+v"(best), [bidx]"+v"(bidx), [va]"+v"(va0)
        : [z0]"v"(Z0),  [z1]"v"(Z1),  [z2]"v"(Z2),  [z3]"v"(Z3),
          [z4]"v"(Z4),  [z5]"v"(Z5),  [z6]"v"(Z6),  [z7]"v"(Z7),
          [z8]"v"(Z8),  [z9]"v"(Z9),  [z10]"v"(Z10), [z11]"v"(Z11),
          [z12]"v"(Z12), [z13]"v"(Z13), [z14]"v"(Z14), [z15]"v"(Z15),
          [z16]"v"(Z16), [z17]"v"(Z17), [z18]"v"(Z18), [z19]"v"(Z19),
          [z20]"v"(Z20), [z21]"v"(Z21), [z22]"v"(Z22), [z23]"v"(Z23),
          [z24]"v"(Z24), [z25]"v"(Z25), [z26]"v"(Z26), [z27]"v"(Z27),
          [z28]"v"(Z28), [z29]"v"(Z29), [z30]"v"(Z30), [z31]"v"(Z31),
          [z32]"v"(Z32), [z33]"v"(Z33), [z34]"v"(Z34), [z35]"v"(Z35),
          [z36]"v"(Z36), [z37]"v"(Z37), [z38]"v"(Z38), [z39]"v"(Z39),
          [z40]"v"(Z40), [z41]"v"(Z41), [z42]"v"(Z42), [z43]"v"(Z43),
          [z44]"v"(Z44), [z45]"v"(Z45), [z46]"v"(Z46), [z47]"v"(Z47),
          [z48]"v"(Z48), [z49]"v"(Z49), [z50]"v"(Z50), [z51]"v"(Z51),
          [z52]"v"(Z52), [z53]"v"(Z53), [z54]"v"(Z54), [z55]"v"(Z55),
          [z56]"v"(Z56), [z57]"v"(Z57), [z58]"v"(Z58), [z59]"v"(Z59),
          [z60]"v"(Z60), [z61]"v"(Z61), [z62]"v"(Z62), [z63]"v"(Z63),
          [A]"v"(A), [n0]"v"(c0i)
        : "s32",
          "v48","v49","v50","v51","v52","v53","v54","v55",
          "v56","v57","v58","v59","v60","v61","v62","v63",
          "v64","v65","v66","v67","v68","v69","v70","v71",
          "v72","v73","v74","v75","v76","v77","v78","v79",
          "v80","v81","v82","v83","v84","v85","v86","v87",
          "v88","v89","v90","v91","v92","v93","v94","v95",
          "v96","v97","v98","v99","v100","v101","v102","v103",
          "v104","v105","v106","v107","v108","v109","v110","v111",
          "v112","v113","v114","v115","v116","v117","v118","v119",
          "vcc","scc","memory");

    // d >= 0 always so float order == uint order; low 32 bits = idx so
    // equal-d ties pick the smaller index (first-occurrence argmin).
    unsigned long long pk =
        ((unsigned long long)__float_as_uint(best) << 32) | (unsigned)bidx;
    atomicMin(&packed[t], pk);
}

// ---- unpack chunk-combined argmin, emit idx + counts ----------------------
__global__ __launch_bounds__(256) void kFinish(const unsigned long long* __restrict__ packed,
                                               float* __restrict__ outIdxF,
                                               int* __restrict__ wsIdx,
                                               unsigned* __restrict__ counts) {
    int t = blockIdx.x * 256 + threadIdx.x;
    int idx = (int)(unsigned)(packed[t] & 0xFFFFFFFFull);
    outIdxF[t] = (float)idx;
    wsIdx[t]   = idx;
    atomicAdd(&counts[idx], 1u);
}

// ---- exclusive prefix sum of counts -> bucket offsets ---------------------
__global__ __launch_bounds__(256) void kOffsets(const unsigned* __restrict__ counts,
                                                unsigned* __restrict__ offsets) {
    __shared__ unsigned psum[256];
    int tid = threadIdx.x;
    unsigned local[16];
    unsigned s = 0;
#pragma unroll
    for (int j = 0; j < 16; ++j) { local[j] = s; s += counts[tid * 16 + j]; }
    psum[tid] = s;
    __syncthreads();
    unsigned base = 0;
    for (int i = 0; i < tid; ++i) base += psum[i];
#pragma unroll
    for (int j = 0; j < 16; ++j) offsets[tid * 16 + j] = base + local[j];
}

// ---- scatter token ids into per-code buckets ------------------------------
__global__ __launch_bounds__(256) void kScatter(const int* __restrict__ wsIdx,
                                                const unsigned* __restrict__ offsets,
                                                unsigned* __restrict__ cursor,
                                                int* __restrict__ bucket) {
    int t = blockIdx.x * 256 + threadIdx.x;
    int idx = wsIdx[t];
    unsigned pos = atomicAdd(&cursor[idx], 1u);
    bucket[offsets[idx] + pos] = t;
}

// ---- streaming epilogue: gather, straight-through out, loss partials ------
__global__ __launch_bounds__(256) void kEpilogue(const float* __restrict__ z,
                                                 const float* __restrict__ e,
                                                 const int* __restrict__ wsIdx,
                                                 float* __restrict__ out,
                                                 double* __restrict__ lossPart) {
    __shared__ double lp[4];
    long g = (long)blockIdx.x * 256 + threadIdx.x;   // 0 .. 4194303 (z-linear)
    int b = (int)(g >> 20);
    int r = (int)(g & 1048575);
    int k = r >> 14;
    int s = r & 16383;
    int t = (b << 14) | s;

    float zv = z[g];
    int n = wsIdx[t];
    float eq = e[(n << 6) + k];
    float diff = eq - zv;            // fl(z_q - zp)
    out[g] = zv + diff;              // fl(zp + fl(z_q - zp))  (straight-through)

    double sq = (double)diff * (double)diff;
#pragma unroll
    for (int o = 32; o > 0; o >>= 1) sq += __shfl_down(sq, o);
    if ((threadIdx.x & 63) == 0) lp[threadIdx.x >> 6] = sq;
    __syncthreads();
    if (threadIdx.x == 0) lossPart[blockIdx.x] = (lp[0] + lp[1]) + (lp[2] + lp[3]);
}

// ---- reduce loss partials -------------------------------------------------
__global__ __launch_bounds__(256) void kLoss(const double* __restrict__ lossPart,
                                             double* __restrict__ acc) {
    __shared__ double lp[4];
    double s = 0.0;
    for (int j = 0; j < 64; ++j) s += lossPart[threadIdx.x + j * 256];
#pragma unroll
    for (int o = 32; o > 0; o >>= 1) s += __shfl_down(s, o);
    if ((threadIdx.x & 63) == 0) lp[threadIdx.x >> 6] = s;
    __syncthreads();
    if (threadIdx.x == 0) acc[0] = (lp[0] + lp[1]) + (lp[2] + lp[3]);
}

// ---- EMA part 1: new_cs, n-sum, perplexity partial ------------------------
__global__ __launch_bounds__(256) void kEma1(const float* __restrict__ cs,
                                             const unsigned* __restrict__ counts,
                                             float* __restrict__ outNcs,
                                             double* __restrict__ acc) {
    int n = blockIdx.x * 256 + threadIdx.x;
    float cf = (float)counts[n];
    float p1 = cs[n] * 0.99f;
    float p2 = 0.01f * cf;
    float ncs = p1 + p2;
    outNcs[n] = ncs;
    float p = cf * (1.0f / 65536.0f);          // exact (pow2 divide)
    float term = p * logf(p + 1e-10f);
    double dn = (double)ncs, dt = (double)term;
#pragma unroll
    for (int o = 32; o > 0; o >>= 1) { dn += __shfl_down(dn, o); dt += __shfl_down(dt, o); }
    if ((threadIdx.x & 63) == 0) {
        atomicAdd(&acc[1], dn);
        atomicAdd(&acc[2], dt);
    }
}

// ---- per-code bucket gather: embed_sum -> new_ea, new_embed; scalars ------
__global__ __launch_bounds__(64) void kEsumEma2(const float* __restrict__ z,
                                                const float* __restrict__ ea,
                                                const int* __restrict__ bucket,
                                                const unsigned* __restrict__ offsets,
                                                const unsigned* __restrict__ counts,
                                                const float* __restrict__ ncsArr,
                                                const double* __restrict__ acc,
                                                float* __restrict__ outNemb,
                                                float* __restrict__ outNea,
                                                float* __restrict__ outLoss,
                                                float* __restrict__ outPerp) {
    int n = blockIdx.x;              // code id
    int k = threadIdx.x;             // dim
    unsigned off = offsets[n];
    unsigned cnt = counts[n];
    float es = 0.f;
    for (unsigned i = 0; i < cnt; ++i) {
        int t = bucket[off + i];
        int b = t >> 14;
        int s = t & 16383;
        es += z[(long)b * 1048576 + k * 16384 + s];
    }
    float nea = ea[(n << 6) + k] * 0.99f + 0.01f * es;
    outNea[(n << 6) + k] = nea;
    float nt = (float)acc[1];
    float ncs = ncsArr[n];
    float sc = ((ncs + 1e-5f) / (nt + 0.04096f)) * nt;
    outNemb[(n << 6) + k] = nea / sc;
    if (n == 0 && k == 0) {
        double m = acc[0] / 4194304.0;
        outLoss[0] = 0.25f * (float)m;
        outPerp[0] = (float)exp(-acc[2]);
    }
}

extern "C" void kernel_launch(void* const* d_in, const int* in_sizes, int n_in,
                              void* d_out, int out_size, void* d_ws, size_t ws_size,
                              hipStream_t stream) {
    const float* z  = (const float*)d_in[0];
    const float* ew = (const float*)d_in[1];
    const float* cs = (const float*)d_in[2];
    const float* ea = (const float*)d_in[3];
    float* out = (float*)d_out;
    char* ws = (char*)d_ws;

    double*   acc    = (double*)(ws + W_ACC);
    unsigned* counts = (unsigned*)(ws + W_CNT);
    unsigned* cursor = (unsigned*)(ws + W_CUR);
    unsigned* offs   = (unsigned*)(ws + W_OFF);
    int*      wsIdx  = (int*)(ws + W_IDX);
    int*      bucket = (int*)(ws + W_BKT);
    double*   lossP  = (double*)(ws + W_LOSSP);
    unsigned long long* packed = (unsigned long long*)(ws + W_PKD);
    float*    aug    = (float*)(ws + W_AUG);

    hipMemsetAsync(ws, 0, W_ZERO_BYTES, stream);
    hipMemsetAsync(ws + W_PKD, 0xFF, W_PKD_BYTES, stream);
    kAug<<<NE / 256, 256, 0, stream>>>(ew, aug);
    kArgmin<<<(NTOK / 256) * NCHUNK, 256, 0, stream>>>(z, aug, packed);
    kFinish<<<NTOK / 256, 256, 0, stream>>>(packed, out + O_IDX, wsIdx, counts);
    kOffsets<<<1, 256, 0, stream>>>(counts, offs);
    kScatter<<<NTOK / 256, 256, 0, stream>>>(wsIdx, offs, cursor, bucket);
    kEpilogue<<<16384, 256, 0, stream>>>(z, ew, wsIdx, out + O_OUT, lossP);
    kLoss<<<1, 256, 0, stream>>>(lossP, acc);
    kEma1<<<NE / 256, 256, 0, stream>>>(cs, counts, out + O_NCS, acc);
    kEsumEma2<<<NE, 64, 0, stream>>>(z, ea, bucket, offs, counts, out + O_NCS, acc,
                                     out + O_NEMB, out + O_NEA,
                                     out + O_LOSS, out + O_PERP);
}